// Round 3
// baseline (109.560 us; speedup 1.0000x reference)
//
#include <hip/hip_runtime.h>

// Problem: B=2,H=8,L=1024,D=64 -> N=16 heads. Chunked causal linear attention.
#define NH   16
#define LSEQ 1024
#define DH   64
#define D2   128
#define TC   64          // chunk length
#define NC   (LSEQ / TC) // 16 chunks
#define WSROWS 65        // 64 v-cols + 1 ksum row
#define WSCH (WSROWS * D2) // 8320 floats per (head, chunk)

#define SCALE 1.53398078788564122971e-3f // (pi/2)/1024

typedef __attribute__((ext_vector_type(8))) short bf16x8;
typedef __attribute__((ext_vector_type(4))) float f32x4;

__device__ __forceinline__ short f2b(float x) {
    union { float f; unsigned u; } v; v.f = x;
    unsigned r = (v.u + 0x7FFFu + ((v.u >> 16) & 1u)) >> 16;
    return (short)r;
}
__device__ __forceinline__ float relu(float x) { return fmaxf(x, 0.f); }

// ---------------------------------------------------------------------------
// A: per (chunk c, head n): ws[m][d2] = sum_l v_ext[l][m] * k_[l][d2]
//    (m<64: V columns; m=64: ones -> k_ column sums). MFMA 16x16x32 bf16.
// ---------------------------------------------------------------------------
__global__ __launch_bounds__(256) void ka_chunk(
    const float* __restrict__ k, const float* __restrict__ v,
    float* __restrict__ ws)
{
    __shared__ __align__(16) short KT[D2][72]; // KT[d2][l]
    __shared__ __align__(16) short VT[80][72]; // VT[m][l], row 64 = ones

    const int c = blockIdx.x, n = blockIdx.y;
    const int t = threadIdx.x;
    const int base = (n * LSEQ + c * TC) * DH;
    const float4* kp = (const float4*)(k + base);
    const float4* vp = (const float4*)(v + base);

    for (int it = 0; it < 4; ++it) {
        int f = t + 256 * it;
        int l = f >> 4, d = (f & 15) * 4;
        float th = SCALE * (float)(c * TC + l + 1);
        float sl = __sinf(th), cl = __cosf(th);
        float4 kk = kp[f];
        float k0 = relu(kk.x), k1 = relu(kk.y), k2 = relu(kk.z), k3 = relu(kk.w);
        KT[d + 0][l] = f2b(k0 * sl); KT[d + 1][l] = f2b(k1 * sl);
        KT[d + 2][l] = f2b(k2 * sl); KT[d + 3][l] = f2b(k3 * sl);
        KT[d + 64][l] = f2b(k0 * cl); KT[d + 65][l] = f2b(k1 * cl);
        KT[d + 66][l] = f2b(k2 * cl); KT[d + 67][l] = f2b(k3 * cl);
        float4 vv = vp[f];
        VT[d + 0][l] = f2b(relu(vv.x)); VT[d + 1][l] = f2b(relu(vv.y));
        VT[d + 2][l] = f2b(relu(vv.z)); VT[d + 3][l] = f2b(relu(vv.w));
    }
    if (t < TC) VT[64][t] = (short)0x3F80; // bf16 1.0
    __syncthreads();

    const int lane = t & 63, w = t >> 6, quad = lane >> 4, r16 = lane & 15;

    bf16x8 af[5][2];
#pragma unroll
    for (int mt = 0; mt < 5; ++mt)
#pragma unroll
        for (int ki = 0; ki < 2; ++ki)
            af[mt][ki] = *(const bf16x8*)&VT[16 * mt + r16][ki * 32 + quad * 8];

    f32x4 acc[5][2];
#pragma unroll
    for (int mt = 0; mt < 5; ++mt)
#pragma unroll
        for (int j = 0; j < 2; ++j) acc[mt][j] = f32x4{0.f, 0.f, 0.f, 0.f};

#pragma unroll
    for (int nti = 0; nti < 2; ++nti) {
        int nt = w + 4 * nti;
#pragma unroll
        for (int ki = 0; ki < 2; ++ki) {
            bf16x8 bf = *(const bf16x8*)&KT[16 * nt + r16][ki * 32 + quad * 8];
#pragma unroll
            for (int mt = 0; mt < 5; ++mt)
                acc[mt][nti] = __builtin_amdgcn_mfma_f32_16x16x32_bf16(
                    af[mt][ki], bf, acc[mt][nti], 0, 0, 0);
        }
    }

    float* wp = ws + (size_t)(n * NC + c) * WSCH;
#pragma unroll
    for (int nti = 0; nti < 2; ++nti) {
        int d2 = 16 * (w + 4 * nti) + r16;
#pragma unroll
        for (int mt = 0; mt < 5; ++mt)
#pragma unroll
            for (int reg = 0; reg < 4; ++reg) {
                int row = 16 * mt + quad * 4 + reg;
                if (row < WSROWS) wp[row * D2 + d2] = acc[mt][nti][reg];
            }
    }
}

// ---------------------------------------------------------------------------
// B: per-head exclusive prefix scan over the 16 chunk-sums, in place.
// ---------------------------------------------------------------------------
__global__ __launch_bounds__(256) void kb_scan(float* __restrict__ ws)
{
    const int s = blockIdx.x;  // 0..4
    const int n = blockIdx.y;  // 0..15
    const int t = threadIdx.x;
    const int start = s * 2048;
    const int cnt = (s == 4) ? 128 : 2048;

    float run[8];
#pragma unroll
    for (int i = 0; i < 8; ++i) run[i] = 0.f;

    float* bp = ws + (size_t)n * NC * WSCH + start;
    for (int c = 0; c < NC; ++c) {
        float* p = bp + (size_t)c * WSCH;
#pragma unroll
        for (int i = 0; i < 8; ++i) {
            int e = t + 256 * i;
            if (e < cnt) {
                float x = p[e];
                p[e] = run[i];
                run[i] += x;
            }
        }
    }
}

// ---------------------------------------------------------------------------
// C: per (chunk, head): S = Q_ K_^T (tril mask) -> P; O = P*V_ext + Q_*KV_ext.
//    Output col 64 = denominator (ones column / kprefix row).
// ---------------------------------------------------------------------------
__global__ __launch_bounds__(256) void kc_out(
    const float* __restrict__ q, const float* __restrict__ k,
    const float* __restrict__ v, const float* __restrict__ ws,
    float* __restrict__ out)
{
    __shared__ __align__(16) short Ks[TC][136];   // k_[l][d2] row-major
    __shared__ __align__(16) short VT[80][72];    // v^T[m][l], row 64 = ones
    __shared__ __align__(16) short KVT[80][136];  // KV^T[m][d2], row 64 = kprefix
    __shared__ __align__(16) short Ps[TC][72];    // masked P[l][j]

    const int c = blockIdx.x, n = blockIdx.y;
    const int t = threadIdx.x;
    const int base = (n * LSEQ + c * TC) * DH;
    const float4* kp = (const float4*)(k + base);
    const float4* vp = (const float4*)(v + base);

    for (int it = 0; it < 4; ++it) {
        int f = t + 256 * it;
        int l = f >> 4, d = (f & 15) * 4;
        float th = SCALE * (float)(c * TC + l + 1);
        float sl = __sinf(th), cl = __cosf(th);
        float4 kk = kp[f];
        float k0 = relu(kk.x), k1 = relu(kk.y), k2 = relu(kk.z), k3 = relu(kk.w);
        Ks[l][d + 0] = f2b(k0 * sl); Ks[l][d + 1] = f2b(k1 * sl);
        Ks[l][d + 2] = f2b(k2 * sl); Ks[l][d + 3] = f2b(k3 * sl);
        Ks[l][d + 64] = f2b(k0 * cl); Ks[l][d + 65] = f2b(k1 * cl);
        Ks[l][d + 66] = f2b(k2 * cl); Ks[l][d + 67] = f2b(k3 * cl);
        float4 vv = vp[f];
        VT[d + 0][l] = f2b(relu(vv.x)); VT[d + 1][l] = f2b(relu(vv.y));
        VT[d + 2][l] = f2b(relu(vv.z)); VT[d + 3][l] = f2b(relu(vv.w));
    }
    if (t < TC) VT[64][t] = (short)0x3F80;
    {
        const float* wp = ws + (size_t)(n * NC + c) * WSCH;
        for (int e = t; e < WSCH; e += 256)
            KVT[e >> 7][e & 127] = f2b(wp[e]);
    }
    __syncthreads();

    const int lane = t & 63, w = t >> 6, quad = lane >> 4, r16 = lane & 15;

    // Q A-frags straight from global (rows = 16w + r16)
    const int lq = 16 * w + r16;
    const float* qrow = q + (size_t)(n * LSEQ + c * TC + lq) * DH;
    float thq = SCALE * (float)(c * TC + lq + 1);
    float sq = __sinf(thq), cq = __cosf(thq);
    bf16x8 qf[4];
#pragma unroll
    for (int ki = 0; ki < 4; ++ki) {
        int d2 = ki * 32 + quad * 8;
        float wgt = (d2 < 64) ? sq : cq;
        const float* p = qrow + (d2 & 63);
        float4 a = *(const float4*)p;
        float4 b = *(const float4*)(p + 4);
        bf16x8 r;
        r[0] = f2b(relu(a.x) * wgt); r[1] = f2b(relu(a.y) * wgt);
        r[2] = f2b(relu(a.z) * wgt); r[3] = f2b(relu(a.w) * wgt);
        r[4] = f2b(relu(b.x) * wgt); r[5] = f2b(relu(b.y) * wgt);
        r[6] = f2b(relu(b.z) * wgt); r[7] = f2b(relu(b.w) * wgt);
        qf[ki] = r;
    }

    // S = Q_ K_^T  (4 n-tiles per wave, K=128)
    f32x4 accS[4];
#pragma unroll
    for (int nt = 0; nt < 4; ++nt) accS[nt] = f32x4{0.f, 0.f, 0.f, 0.f};
#pragma unroll
    for (int nt = 0; nt < 4; ++nt)
#pragma unroll
        for (int ki = 0; ki < 4; ++ki) {
            bf16x8 kf = *(const bf16x8*)&Ks[16 * nt + r16][ki * 32 + quad * 8];
            accS[nt] = __builtin_amdgcn_mfma_f32_16x16x32_bf16(qf[ki], kf, accS[nt], 0, 0, 0);
        }

    // tril mask (j <= l) -> bf16 P in LDS
#pragma unroll
    for (int nt = 0; nt < 4; ++nt)
#pragma unroll
        for (int reg = 0; reg < 4; ++reg) {
            int row = 16 * w + quad * 4 + reg;
            int col = 16 * nt + r16;
            float pv = (col <= row) ? accS[nt][reg] : 0.f;
            Ps[row][col] = f2b(pv);
        }
    __syncthreads();

    // O = P * V_ext + Q_ * KV_ext   (5 n-tiles: cols 0..63 out, col 64 denom)
    bf16x8 pf[2];
#pragma unroll
    for (int ki = 0; ki < 2; ++ki)
        pf[ki] = *(const bf16x8*)&Ps[16 * w + r16][ki * 32 + quad * 8];

    f32x4 accO[5];
#pragma unroll
    for (int nt = 0; nt < 5; ++nt) accO[nt] = f32x4{0.f, 0.f, 0.f, 0.f};
#pragma unroll
    for (int nt = 0; nt < 5; ++nt) {
#pragma unroll
        for (int ki = 0; ki < 2; ++ki) {
            bf16x8 vf = *(const bf16x8*)&VT[16 * nt + r16][ki * 32 + quad * 8];
            accO[nt] = __builtin_amdgcn_mfma_f32_16x16x32_bf16(pf[ki], vf, accO[nt], 0, 0, 0);
        }
#pragma unroll
        for (int ki = 0; ki < 4; ++ki) {
            bf16x8 kvf = *(const bf16x8*)&KVT[16 * nt + r16][ki * 32 + quad * 8];
            accO[nt] = __builtin_amdgcn_mfma_f32_16x16x32_bf16(qf[ki], kvf, accO[nt], 0, 0, 0);
        }
    }

    // epilogue: denom = col 64 (held by lanes r16==0), broadcast within quad group
    const int src = lane & 48;
#pragma unroll
    for (int reg = 0; reg < 4; ++reg) {
        float den = __shfl(accO[4][reg], src, 64);
        den = fmaxf(den, 1e-6f);
        float inv = 1.0f / den;
        int l = c * TC + 16 * w + quad * 4 + reg;
        float* orow = out + (size_t)(n * LSEQ + l) * DH;
#pragma unroll
        for (int nt = 0; nt < 4; ++nt)
            orow[16 * nt + r16] = accO[nt][reg] * inv;
    }
}

// ---------------------------------------------------------------------------
extern "C" void kernel_launch(void* const* d_in, const int* in_sizes, int n_in,
                              void* d_out, int out_size, void* d_ws, size_t ws_size,
                              hipStream_t stream) {
    (void)in_sizes; (void)n_in; (void)out_size; (void)ws_size;
    const float* q = (const float*)d_in[0];
    const float* k = (const float*)d_in[1];
    const float* v = (const float*)d_in[2];
    float* out = (float*)d_out;
    float* ws = (float*)d_ws; // 16*16*8320*4 = 8.52 MB

    dim3 ga(NC, NH);
    ka_chunk<<<ga, 256, 0, stream>>>(k, v, ws);
    dim3 gb(5, NH);
    kb_scan<<<gb, 256, 0, stream>>>(ws);
    dim3 gc(NC, NH);
    kc_out<<<gc, 256, 0, stream>>>(q, k, v, ws, out);
}